// Round 3
// baseline (39848.950 us; speedup 1.0000x reference)
//
#include <hip/hip_runtime.h>
#include <hip/hip_bf16.h>
#include <hip/hip_cooperative_groups.h>
#include <math.h>

namespace cg = cooperative_groups;

typedef short bf16x8 __attribute__((ext_vector_type(8)));
typedef float f32x4 __attribute__((ext_vector_type(4)));
typedef unsigned short u16;

#define NT 64
#define NB 512
#define NS 256
#define NA 64
#define NBEL 1024

// d_out element offsets (f32 elements)
#define OUT_B      0
#define OUT_SPRI   33554432
#define OUT_MUPRI  41943040
#define OUT_STDPRI 50331648
#define OUT_SPOS   58720256
#define OUT_MUPOS  67108864
#define OUT_STDPOS 75497472

__device__ __forceinline__ f32x4 mfma16(bf16x8 a, bf16x8 b, f32x4 c) {
  return __builtin_amdgcn_mfma_f32_16x16x32_bf16(a, b, c, 0, 0, 0);
}

__device__ __forceinline__ u16 f2bf(float f) {
  union { float f; unsigned u; } v; v.f = f;
  return (u16)((v.u + 0x7FFFu + ((v.u >> 16) & 1u)) >> 16);
}

__device__ __forceinline__ bf16x8 ld8bf(const u16* p) { return *(const bf16x8*)p; }

__device__ __forceinline__ bf16x8 cvt8(const float* p) {
  const float4 lo = *(const float4*)p;
  const float4 hi = *(const float4*)(p + 4);
  bf16x8 v;
  v[0] = (short)f2bf(lo.x); v[1] = (short)f2bf(lo.y);
  v[2] = (short)f2bf(lo.z); v[3] = (short)f2bf(lo.w);
  v[4] = (short)f2bf(hi.x); v[5] = (short)f2bf(hi.y);
  v[6] = (short)f2bf(hi.z); v[7] = (short)f2bf(hi.w);
  return v;
}

__device__ __forceinline__ float sigm(float x) { return 1.f / (1.f + __expf(-x)); }
__device__ __forceinline__ float softplus_(float x) {
  if (x > 20.f) return x;
  return log1pf(__expf(x));
}

#define ZACC(acc) { acc[0][0] = (f32x4){0.f,0.f,0.f,0.f}; acc[0][1] = (f32x4){0.f,0.f,0.f,0.f}; \
                    acc[1][0] = (f32x4){0.f,0.f,0.f,0.f}; acc[1][1] = (f32x4){0.f,0.f,0.f,0.f}; }

#define Q4(acc, a0v, a1v, b0v, b1v) \
  acc[0][0] = mfma16(a0v, b0v, acc[0][0]); \
  acc[0][1] = mfma16(a0v, b1v, acc[0][1]); \
  acc[1][0] = mfma16(a1v, b0v, acc[1][0]); \
  acc[1][1] = mfma16(a1v, b1v, acc[1][1]);

// ======================= cooperative fused kernel =======================
struct RP {
  const float *Af, *Of, *Mp, *npri, *npos;
  const float *bsa, *bih, *bhh, *bbpri, *bspri, *bbpos, *bspos;
  const float *s0, *b0;
  const float *Wsa, *Wih, *Whh, *Wbpri, *Wspri, *Wbpos, *Wspos;
  float *out, *hf, *gh;
  u16 *wbase, *smask, *bbf0, *bbf1, *xbf, *hbbf, *hpri;
};

__global__ void __launch_bounds__(256, 2) rssm_fused(RP p) {
  cg::grid_group gridg = cg::this_grid();
  const int tid = blockIdx.x * 256 + threadIdx.x;  // 0..131071
  const int w = tid >> 6;                          // global wave 0..2047
  const int l = threadIdx.x & 63;
  const int r16 = l & 15, kq = l >> 4;

  const u16* wsa   = p.wbase;
  const u16* wih   = p.wbase + 327680;
  const u16* whh   = p.wbase + 3473408;
  const u16* wbpri = p.wbase + 6619136;
  const u16* wspri = p.wbase + 7667712;
  const u16* wbpos = p.wbase + 8192000;
  const u16* wspos = p.wbase + 10289152;

  // ---------------- prologue: cvt weights + init carries ----------------
  {
    const int S0 = 327680;
    const int S1 = S0 + 3145728;
    const int S2 = S1 + 3145728;
    const int S3 = S2 + 1048576;
    const int S4 = S3 + 524288;
    const int S5 = S4 + 2097152;
    const int S6 = S5 + 524288;
    for (int i = tid; i < S6; i += 131072) {
      float v;
      if (i < S0) v = p.Wsa[i];
      else if (i < S1) v = p.Wih[i - S0];
      else if (i < S2) v = p.Whh[i - S1];
      else if (i < S3) v = p.Wbpri[i - S2];
      else if (i < S4) v = p.Wspri[i - S3];
      else if (i < S5) v = p.Wbpos[i - S4];
      else v = p.Wspos[i - S5];
      p.wbase[i] = f2bf(v);
    }
    for (int i = tid; i < NB * NBEL; i += 131072) {
      float b = p.b0[i];
      p.bbf0[i] = f2bf(b);
      p.hf[i] = b;
    }
    // NB*NS == 131072 exactly: one element per thread
    p.smask[tid] = f2bf(p.s0[tid] * p.Mp[tid >> 8]);
  }
  __threadfence();
  gridg.sync();

  for (int t = 0; t <= NT; ++t) {
    const u16* bprev = (t & 1) ? p.bbf1 : p.bbf0;  // bnew_{t-1} (b0 at t=0)
    u16* bcur = (t & 1) ? p.bbf0 : p.bbf1;         // bnew_t written in P2

    // ---------------- P1: x (512 waves) | gh (1536 waves) ----------------
    if (t < NT) {
      if (w < 512) {
        const int row0 = (w >> 5) * 32, col0 = (w & 31) * 32;
        f32x4 acc[2][2]; ZACC(acc);
        {
          const u16* A0 = p.smask + (row0 + r16) * NS + kq * 8;
          const u16* A1 = A0 + 16 * NS;
          const u16* B0 = wsa + (size_t)(col0 + r16) * 320 + kq * 8;
          const u16* B1 = B0 + 16 * 320;
#pragma unroll
          for (int k = 0; k < 256; k += 32) {
            bf16x8 a0 = ld8bf(A0 + k), a1 = ld8bf(A1 + k);
            bf16x8 b0 = ld8bf(B0 + k), b1 = ld8bf(B1 + k);
            Q4(acc, a0, a1, b0, b1);
          }
        }
        {
          const float* A0 = p.Af + (size_t)t * (NB * NA) + (row0 + r16) * NA + kq * 8;
          const float* A1 = A0 + 16 * NA;
          const u16* B0 = wsa + (size_t)(col0 + r16) * 320 + 256 + kq * 8;
          const u16* B1 = B0 + 16 * 320;
#pragma unroll
          for (int k = 0; k < 64; k += 32) {
            bf16x8 a0 = cvt8(A0 + k), a1 = cvt8(A1 + k);
            bf16x8 b0 = ld8bf(B0 + k), b1 = ld8bf(B1 + k);
            Q4(acc, a0, a1, b0, b1);
          }
        }
#pragma unroll
        for (int i = 0; i < 2; ++i)
#pragma unroll
          for (int j = 0; j < 2; ++j)
#pragma unroll
            for (int q = 0; q < 4; ++q) {
              const int row = row0 + i * 16 + kq * 4 + q;
              const int col = col0 + j * 16 + r16;
              p.xbf[row * NBEL + col] = f2bf(fmaxf(acc[i][j][q] + p.bsa[col], 0.f));
            }
      } else {
        const int v = w - 512;                    // 0..1535
        const int row0 = (v / 96) * 32, col0 = (v % 96) * 32;
        f32x4 acc[2][2]; ZACC(acc);
        const u16* A0 = bprev + (row0 + r16) * NBEL + kq * 8;
        const u16* A1 = A0 + 16 * NBEL;
        const u16* B0 = whh + (size_t)(col0 + r16) * NBEL + kq * 8;
        const u16* B1 = B0 + 16 * NBEL;
        for (int k = 0; k < NBEL; k += 32) {
          bf16x8 a0 = ld8bf(A0 + k), a1 = ld8bf(A1 + k);
          bf16x8 b0 = ld8bf(B0 + k), b1 = ld8bf(B1 + k);
          Q4(acc, a0, a1, b0, b1);
        }
#pragma unroll
        for (int i = 0; i < 2; ++i)
#pragma unroll
          for (int j = 0; j < 2; ++j)
#pragma unroll
            for (int q = 0; q < 4; ++q) {
              const int row = row0 + i * 16 + kq * 4 + q;
              const int col = col0 + j * 16 + r16;
              p.gh[row * 3072 + col] = acc[i][j][q] + p.bhh[col];
            }
      }
    }
    __threadfence();
    gridg.sync();

    // ---------------- P2: gi+GRU (512) | bpri(t-1) (512) ----------------
    if (t < NT && w < 512) {
      const int row0 = (w >> 5) * 32, col0 = (w & 31) * 32;
      f32x4 ar[2][2], az[2][2], an[2][2];
      ZACC(ar); ZACC(az); ZACC(an);
      const u16* A0 = p.xbf + (row0 + r16) * NBEL + kq * 8;
      const u16* A1 = A0 + 16 * NBEL;
      const u16* Br0 = wih + (size_t)(col0 + r16) * NBEL + kq * 8;
      const u16* Br1 = Br0 + 16 * NBEL;
      const u16* Bz0 = wih + (size_t)(col0 + 1024 + r16) * NBEL + kq * 8;
      const u16* Bz1 = Bz0 + 16 * NBEL;
      const u16* Bn0 = wih + (size_t)(col0 + 2048 + r16) * NBEL + kq * 8;
      const u16* Bn1 = Bn0 + 16 * NBEL;
      for (int k = 0; k < NBEL; k += 32) {
        bf16x8 a0 = ld8bf(A0 + k), a1 = ld8bf(A1 + k);
        bf16x8 b0 = ld8bf(Br0 + k), b1 = ld8bf(Br1 + k);
        Q4(ar, a0, a1, b0, b1);
        bf16x8 c0 = ld8bf(Bz0 + k), c1 = ld8bf(Bz1 + k);
        Q4(az, a0, a1, c0, c1);
        bf16x8 d0 = ld8bf(Bn0 + k), d1 = ld8bf(Bn1 + k);
        Q4(an, a0, a1, d0, d1);
      }
#pragma unroll
      for (int i = 0; i < 2; ++i)
#pragma unroll
        for (int j = 0; j < 2; ++j)
#pragma unroll
          for (int q = 0; q < 4; ++q) {
            const int row = row0 + i * 16 + kq * 4 + q;
            const int c = col0 + j * 16 + r16;
            const float gir = ar[i][j][q] + p.bih[c];
            const float giz = az[i][j][q] + p.bih[c + 1024];
            const float gin = an[i][j][q] + p.bih[c + 2048];
            const float* ghrow = p.gh + row * 3072;
            const float r = sigm(gir + ghrow[c]);
            const float z = sigm(giz + ghrow[c + 1024]);
            const float n = tanhf(gin + r * ghrow[c + 2048]);
            const float h = p.hf[row * NBEL + c];
            const float bnew = (1.f - z) * n + z * h;
            p.hf[row * NBEL + c] = bnew;
            bcur[row * NBEL + c] = f2bf(bnew);
            p.out[OUT_B + (size_t)t * (NB * NBEL) + row * NBEL + c] = bnew;
          }
    } else if (t > 0 && w >= 512 && w < 1024) {
      const int v = w - 512;
      const int row0 = (v >> 5) * 32, col0 = (v & 31) * 32;
      f32x4 acc[2][2]; ZACC(acc);
      const u16* A0 = bprev + (row0 + r16) * NBEL + kq * 8;
      const u16* A1 = A0 + 16 * NBEL;
      const u16* B0 = wbpri + (size_t)(col0 + r16) * NBEL + kq * 8;
      const u16* B1 = B0 + 16 * NBEL;
      for (int k = 0; k < NBEL; k += 32) {
        bf16x8 a0 = ld8bf(A0 + k), a1 = ld8bf(A1 + k);
        bf16x8 b0 = ld8bf(B0 + k), b1 = ld8bf(B1 + k);
        Q4(acc, a0, a1, b0, b1);
      }
#pragma unroll
      for (int i = 0; i < 2; ++i)
#pragma unroll
        for (int j = 0; j < 2; ++j)
#pragma unroll
          for (int q = 0; q < 4; ++q) {
            const int row = row0 + i * 16 + kq * 4 + q;
            const int col = col0 + j * 16 + r16;
            p.hpri[row * NBEL + col] = f2bf(fmaxf(acc[i][j][q] + p.bbpri[col], 0.f));
          }
    }
    __threadfence();
    gridg.sync();

    // ---------------- P3: hb (512) | spri(t-1) (128) ----------------
    if (t < NT && w < 512) {
      const int row0 = (w >> 5) * 32, col0 = (w & 31) * 32;
      f32x4 acc[2][2]; ZACC(acc);
      {
        const u16* A0 = bcur + (row0 + r16) * NBEL + kq * 8;
        const u16* A1 = A0 + 16 * NBEL;
        const u16* B0 = wbpos + (size_t)(col0 + r16) * 2048 + kq * 8;
        const u16* B1 = B0 + 16 * 2048;
        for (int k = 0; k < NBEL; k += 32) {
          bf16x8 a0 = ld8bf(A0 + k), a1 = ld8bf(A1 + k);
          bf16x8 b0 = ld8bf(B0 + k), b1 = ld8bf(B1 + k);
          Q4(acc, a0, a1, b0, b1);
        }
      }
      {
        const float* F0 = p.Of + (size_t)t * (NB * NBEL) + (row0 + r16) * NBEL + kq * 8;
        const float* F1 = F0 + 16 * NBEL;
        const u16* B0 = wbpos + (size_t)(col0 + r16) * 2048 + 1024 + kq * 8;
        const u16* B1 = B0 + 16 * 2048;
        for (int k = 0; k < NBEL; k += 32) {
          bf16x8 a0 = cvt8(F0 + k), a1 = cvt8(F1 + k);
          bf16x8 b0 = ld8bf(B0 + k), b1 = ld8bf(B1 + k);
          Q4(acc, a0, a1, b0, b1);
        }
      }
#pragma unroll
      for (int i = 0; i < 2; ++i)
#pragma unroll
        for (int j = 0; j < 2; ++j)
#pragma unroll
          for (int q = 0; q < 4; ++q) {
            const int row = row0 + i * 16 + kq * 4 + q;
            const int col = col0 + j * 16 + r16;
            p.hbbf[row * NBEL + col] = f2bf(fmaxf(acc[i][j][q] + p.bbpos[col], 0.f));
          }
    } else if (t > 0 && w >= 512 && w < 640) {
      const int v = w - 512;                      // 0..127
      const int row0 = (v >> 3) * 32, c0 = (v & 7) * 32;
      f32x4 am[2][2], ah[2][2];
      ZACC(am); ZACC(ah);
      const u16* A0 = p.hpri + (row0 + r16) * NBEL + kq * 8;
      const u16* A1 = A0 + 16 * NBEL;
      const u16* Bm0 = wspri + (size_t)(c0 + r16) * NBEL + kq * 8;
      const u16* Bm1 = Bm0 + 16 * NBEL;
      const u16* Bh0 = wspri + (size_t)(c0 + 256 + r16) * NBEL + kq * 8;
      const u16* Bh1 = Bh0 + 16 * NBEL;
      for (int k = 0; k < NBEL; k += 32) {
        bf16x8 a0 = ld8bf(A0 + k), a1 = ld8bf(A1 + k);
        bf16x8 m0 = ld8bf(Bm0 + k), m1 = ld8bf(Bm1 + k);
        Q4(am, a0, a1, m0, m1);
        bf16x8 h0 = ld8bf(Bh0 + k), h1 = ld8bf(Bh1 + k);
        Q4(ah, a0, a1, h0, h1);
      }
      const int tt = t - 1;
#pragma unroll
      for (int i = 0; i < 2; ++i)
#pragma unroll
        for (int j = 0; j < 2; ++j)
#pragma unroll
          for (int q = 0; q < 4; ++q) {
            const int row = row0 + i * 16 + kq * 4 + q;
            const int c = c0 + j * 16 + r16;
            const size_t idx = (size_t)tt * (NB * NS) + row * NS + c;
            const float mu = am[i][j][q] + p.bspri[c];
            const float hp = ah[i][j][q] + p.bspri[c + 256];
            const float sd = softplus_(hp) + 0.1f;
            p.out[OUT_SPRI + idx] = mu + sd * p.npri[idx];
            p.out[OUT_MUPRI + idx] = mu;
            p.out[OUT_STDPRI + idx] = sd;
          }
    }
    __threadfence();
    gridg.sync();

    // ---------------- P4: spos (128 waves) ----------------
    if (t < NT && w < 128) {
      const int row0 = (w >> 3) * 32, c0 = (w & 7) * 32;
      f32x4 am[2][2], ah[2][2];
      ZACC(am); ZACC(ah);
      const u16* A0 = p.hbbf + (row0 + r16) * NBEL + kq * 8;
      const u16* A1 = A0 + 16 * NBEL;
      const u16* Bm0 = wspos + (size_t)(c0 + r16) * NBEL + kq * 8;
      const u16* Bm1 = Bm0 + 16 * NBEL;
      const u16* Bh0 = wspos + (size_t)(c0 + 256 + r16) * NBEL + kq * 8;
      const u16* Bh1 = Bh0 + 16 * NBEL;
      for (int k = 0; k < NBEL; k += 32) {
        bf16x8 a0 = ld8bf(A0 + k), a1 = ld8bf(A1 + k);
        bf16x8 m0 = ld8bf(Bm0 + k), m1 = ld8bf(Bm1 + k);
        Q4(am, a0, a1, m0, m1);
        bf16x8 h0 = ld8bf(Bh0 + k), h1 = ld8bf(Bh1 + k);
        Q4(ah, a0, a1, h0, h1);
      }
#pragma unroll
      for (int i = 0; i < 2; ++i)
#pragma unroll
        for (int j = 0; j < 2; ++j)
#pragma unroll
          for (int q = 0; q < 4; ++q) {
            const int row = row0 + i * 16 + kq * 4 + q;
            const int c = c0 + j * 16 + r16;
            const float mu = am[i][j][q] + p.bspos[c];
            const float hq = ah[i][j][q] + p.bspos[c + 256];
            const float sd = softplus_(hq) + 0.1f;
            const size_t idx = (size_t)t * (NB * NS) + row * NS + c;
            const float sq = mu + sd * p.npos[idx];
            p.out[OUT_SPOS + idx] = sq;
            p.out[OUT_MUPOS + idx] = mu;
            p.out[OUT_STDPOS + idx] = sd;
            const float mn = (t < NT - 1) ? p.Mp[(t + 1) * NB + row] : 1.f;
            p.smask[row * NS + c] = f2bf(sq * mn);
          }
    }
    __threadfence();
    gridg.sync();
  }
}

// ======================= fallback path (proven round-2 kernels) =======================
__global__ __launch_bounds__(256) void cvt_weights_k(
    const float* __restrict__ wsa, const float* __restrict__ wih,
    const float* __restrict__ whh, const float* __restrict__ wbpri,
    const float* __restrict__ wspri, const float* __restrict__ wbpos,
    const float* __restrict__ wspos, u16* __restrict__ dst) {
  const int S0 = 327680;
  const int S1 = S0 + 3145728;
  const int S2 = S1 + 3145728;
  const int S3 = S2 + 1048576;
  const int S4 = S3 + 524288;
  const int S5 = S4 + 2097152;
  const int S6 = S5 + 524288;
  for (int i = blockIdx.x * blockDim.x + threadIdx.x; i < S6;
       i += gridDim.x * blockDim.x) {
    float v;
    if (i < S0) v = wsa[i];
    else if (i < S1) v = wih[i - S0];
    else if (i < S2) v = whh[i - S1];
    else if (i < S3) v = wbpri[i - S2];
    else if (i < S4) v = wspri[i - S3];
    else if (i < S5) v = wbpos[i - S4];
    else v = wspos[i - S5];
    dst[i] = f2bf(v);
  }
}

__global__ __launch_bounds__(256) void init_carry_k(
    const float* __restrict__ s0, const float* __restrict__ b0,
    const float* __restrict__ Mptr, u16* __restrict__ smask,
    u16* __restrict__ bbf, float* __restrict__ hf) {
  for (int i = blockIdx.x * blockDim.x + threadIdx.x; i < NB * NBEL;
       i += gridDim.x * blockDim.x) {
    float b = b0[i];
    bbf[i] = f2bf(b);
    hf[i] = b;
    if (i < NB * NS) {
      int row = i >> 8;
      smask[i] = f2bf(s0[i] * Mptr[row]);
    }
  }
}

__global__ __launch_bounds__(256) void k1_x_gh(
    const u16* __restrict__ smask, const float* __restrict__ Af,
    const u16* __restrict__ wsa, const float* __restrict__ b_sa,
    const u16* __restrict__ bbf, const u16* __restrict__ whh,
    const float* __restrict__ b_hh, u16* __restrict__ xbf,
    float* __restrict__ gh, int t) {
  const int l = threadIdx.x & 63, r16 = l & 15, kq = l >> 4;
  const int wid = threadIdx.x >> 6;
  const int bid = blockIdx.x;
  if (bid < 128) {
    const int bm = bid & 7, bn = bid >> 3;
    const int row0 = bm * 64 + (wid >> 1) * 32;
    const int col0 = bn * 64 + (wid & 1) * 32;
    f32x4 acc[2][2]; ZACC(acc);
    {
      const u16* A0 = smask + (row0 + r16) * NS + kq * 8;
      const u16* A1 = A0 + 16 * NS;
      const u16* B0 = wsa + (size_t)(col0 + r16) * 320 + kq * 8;
      const u16* B1 = B0 + 16 * 320;
#pragma unroll
      for (int k = 0; k < NS; k += 32) {
        bf16x8 a0 = ld8bf(A0 + k), a1 = ld8bf(A1 + k);
        bf16x8 b0 = ld8bf(B0 + k), b1 = ld8bf(B1 + k);
        Q4(acc, a0, a1, b0, b1);
      }
    }
    {
      const float* A0 = Af + (size_t)t * NB * NA + (row0 + r16) * NA + kq * 8;
      const float* A1 = A0 + 16 * NA;
      const u16* B0 = wsa + (size_t)(col0 + r16) * 320 + 256 + kq * 8;
      const u16* B1 = B0 + 16 * 320;
#pragma unroll
      for (int k = 0; k < NA; k += 32) {
        bf16x8 a0 = cvt8(A0 + k), a1 = cvt8(A1 + k);
        bf16x8 b0 = ld8bf(B0 + k), b1 = ld8bf(B1 + k);
        Q4(acc, a0, a1, b0, b1);
      }
    }
#pragma unroll
    for (int i = 0; i < 2; ++i)
#pragma unroll
      for (int j = 0; j < 2; ++j)
#pragma unroll
        for (int q = 0; q < 4; ++q) {
          const int row = row0 + i * 16 + kq * 4 + q;
          const int col = col0 + j * 16 + r16;
          const float v = acc[i][j][q] + b_sa[col];
          xbf[row * NBEL + col] = f2bf(fmaxf(v, 0.f));
        }
  } else {
    const int b2 = bid - 128;
    const int bm = b2 & 7, bn = b2 >> 3;
    const int row0 = bm * 64 + (wid >> 1) * 32;
    const int col0 = bn * 64 + (wid & 1) * 32;
    f32x4 acc[2][2]; ZACC(acc);
    const u16* A0 = bbf + (row0 + r16) * NBEL + kq * 8;
    const u16* A1 = A0 + 16 * NBEL;
    const u16* B0 = whh + (size_t)(col0 + r16) * NBEL + kq * 8;
    const u16* B1 = B0 + 16 * NBEL;
    for (int k = 0; k < NBEL; k += 32) {
      bf16x8 a0 = ld8bf(A0 + k), a1 = ld8bf(A1 + k);
      bf16x8 b0 = ld8bf(B0 + k), b1 = ld8bf(B1 + k);
      Q4(acc, a0, a1, b0, b1);
    }
#pragma unroll
    for (int i = 0; i < 2; ++i)
#pragma unroll
      for (int j = 0; j < 2; ++j)
#pragma unroll
        for (int q = 0; q < 4; ++q) {
          const int row = row0 + i * 16 + kq * 4 + q;
          const int col = col0 + j * 16 + r16;
          gh[row * 3072 + col] = acc[i][j][q] + b_hh[col];
        }
  }
}

__global__ __launch_bounds__(256) void k2_gi_gru(
    const u16* __restrict__ xbf, const u16* __restrict__ wih,
    const float* __restrict__ b_ih, const float* __restrict__ gh,
    float* __restrict__ hf, u16* __restrict__ bbf,
    float* __restrict__ out, int t) {
  const int l = threadIdx.x & 63, r16 = l & 15, kq = l >> 4;
  const int wid = threadIdx.x >> 6;
  const int bm = blockIdx.x & 7, bn = blockIdx.x >> 3;
  const int row0 = bm * 64 + (wid >> 1) * 32;
  const int col0 = bn * 64 + (wid & 1) * 32;
  f32x4 ar[2][2], az[2][2], an[2][2];
  ZACC(ar); ZACC(az); ZACC(an);
  const u16* A0 = xbf + (row0 + r16) * NBEL + kq * 8;
  const u16* A1 = A0 + 16 * NBEL;
  const u16* Br0 = wih + (size_t)(col0 + r16) * NBEL + kq * 8;
  const u16* Br1 = Br0 + 16 * NBEL;
  const u16* Bz0 = wih + (size_t)(col0 + 1024 + r16) * NBEL + kq * 8;
  const u16* Bz1 = Bz0 + 16 * NBEL;
  const u16* Bn0 = wih + (size_t)(col0 + 2048 + r16) * NBEL + kq * 8;
  const u16* Bn1 = Bn0 + 16 * NBEL;
  for (int k = 0; k < NBEL; k += 32) {
    bf16x8 a0 = ld8bf(A0 + k), a1 = ld8bf(A1 + k);
    bf16x8 b0 = ld8bf(Br0 + k), b1 = ld8bf(Br1 + k);
    Q4(ar, a0, a1, b0, b1);
    bf16x8 c0 = ld8bf(Bz0 + k), c1 = ld8bf(Bz1 + k);
    Q4(az, a0, a1, c0, c1);
    bf16x8 d0 = ld8bf(Bn0 + k), d1 = ld8bf(Bn1 + k);
    Q4(an, a0, a1, d0, d1);
  }
#pragma unroll
  for (int i = 0; i < 2; ++i)
#pragma unroll
    for (int j = 0; j < 2; ++j)
#pragma unroll
      for (int q = 0; q < 4; ++q) {
        const int row = row0 + i * 16 + kq * 4 + q;
        const int c = col0 + j * 16 + r16;
        const float gir = ar[i][j][q] + b_ih[c];
        const float giz = az[i][j][q] + b_ih[c + 1024];
        const float gin = an[i][j][q] + b_ih[c + 2048];
        const float* ghrow = gh + row * 3072;
        const float r = sigm(gir + ghrow[c]);
        const float z = sigm(giz + ghrow[c + 1024]);
        const float n = tanhf(gin + r * ghrow[c + 2048]);
        const float h = hf[row * NBEL + c];
        const float bnew = (1.f - z) * n + z * h;
        hf[row * NBEL + c] = bnew;
        bbf[row * NBEL + c] = f2bf(bnew);
        out[OUT_B + (size_t)t * (NB * NBEL) + row * NBEL + c] = bnew;
      }
}

__global__ __launch_bounds__(256) void k3_hb(
    const u16* __restrict__ bbf, const float* __restrict__ Of,
    const u16* __restrict__ wbpos, const float* __restrict__ b_bpos,
    u16* __restrict__ hbbf, int t) {
  const int l = threadIdx.x & 63, r16 = l & 15, kq = l >> 4;
  const int wid = threadIdx.x >> 6;
  const int bm = blockIdx.x & 7, bn = blockIdx.x >> 3;
  const int row0 = bm * 64 + (wid >> 1) * 32;
  const int col0 = bn * 64 + (wid & 1) * 32;
  f32x4 acc[2][2]; ZACC(acc);
  {
    const u16* A0 = bbf + (row0 + r16) * NBEL + kq * 8;
    const u16* A1 = A0 + 16 * NBEL;
    const u16* B0 = wbpos + (size_t)(col0 + r16) * 2048 + kq * 8;
    const u16* B1 = B0 + 16 * 2048;
    for (int k = 0; k < NBEL; k += 32) {
      bf16x8 a0 = ld8bf(A0 + k), a1 = ld8bf(A1 + k);
      bf16x8 b0 = ld8bf(B0 + k), b1 = ld8bf(B1 + k);
      Q4(acc, a0, a1, b0, b1);
    }
  }
  {
    const float* F0 = Of + (size_t)t * (NB * NBEL) + (row0 + r16) * NBEL + kq * 8;
    const float* F1 = F0 + 16 * NBEL;
    const u16* B0 = wbpos + (size_t)(col0 + r16) * 2048 + 1024 + kq * 8;
    const u16* B1 = B0 + 16 * 2048;
    for (int k = 0; k < NBEL; k += 32) {
      bf16x8 a0 = cvt8(F0 + k), a1 = cvt8(F1 + k);
      bf16x8 b0 = ld8bf(B0 + k), b1 = ld8bf(B1 + k);
      Q4(acc, a0, a1, b0, b1);
    }
  }
#pragma unroll
  for (int i = 0; i < 2; ++i)
#pragma unroll
    for (int j = 0; j < 2; ++j)
#pragma unroll
      for (int q = 0; q < 4; ++q) {
        const int row = row0 + i * 16 + kq * 4 + q;
        const int col = col0 + j * 16 + r16;
        const float v = acc[i][j][q] + b_bpos[col];
        hbbf[row * NBEL + col] = f2bf(fmaxf(v, 0.f));
      }
}

__global__ __launch_bounds__(256) void k4_spos(
    const u16* __restrict__ hbbf, const u16* __restrict__ wspos,
    const float* __restrict__ b_spos, const float* __restrict__ npos,
    const float* __restrict__ Mptr, float* __restrict__ out,
    u16* __restrict__ smask, int t) {
  const int l = threadIdx.x & 63, r16 = l & 15, kq = l >> 4;
  const int wid = threadIdx.x >> 6;
  const int bm = blockIdx.x & 7, bn = blockIdx.x >> 3;
  const int row0 = bm * 64 + (wid >> 1) * 32;
  const int c0 = bn * 64 + (wid & 1) * 32;
  f32x4 am[2][2], ah[2][2];
  ZACC(am); ZACC(ah);
  const u16* A0 = hbbf + (row0 + r16) * NBEL + kq * 8;
  const u16* A1 = A0 + 16 * NBEL;
  const u16* Bm0 = wspos + (size_t)(c0 + r16) * NBEL + kq * 8;
  const u16* Bm1 = Bm0 + 16 * NBEL;
  const u16* Bh0 = wspos + (size_t)(c0 + 256 + r16) * NBEL + kq * 8;
  const u16* Bh1 = Bh0 + 16 * NBEL;
  for (int k = 0; k < NBEL; k += 32) {
    bf16x8 a0 = ld8bf(A0 + k), a1 = ld8bf(A1 + k);
    bf16x8 m0 = ld8bf(Bm0 + k), m1 = ld8bf(Bm1 + k);
    Q4(am, a0, a1, m0, m1);
    bf16x8 h0 = ld8bf(Bh0 + k), h1 = ld8bf(Bh1 + k);
    Q4(ah, a0, a1, h0, h1);
  }
#pragma unroll
  for (int i = 0; i < 2; ++i)
#pragma unroll
    for (int j = 0; j < 2; ++j)
#pragma unroll
      for (int q = 0; q < 4; ++q) {
        const int row = row0 + i * 16 + kq * 4 + q;
        const int c = c0 + j * 16 + r16;
        const float mu = am[i][j][q] + b_spos[c];
        const float hq = ah[i][j][q] + b_spos[c + 256];
        const float sd = softplus_(hq) + 0.1f;
        const size_t idx = (size_t)t * (NB * NS) + row * NS + c;
        const float sq = mu + sd * npos[idx];
        out[OUT_SPOS + idx] = sq;
        out[OUT_MUPOS + idx] = mu;
        out[OUT_STDPOS + idx] = sd;
        const float mn = (t < NT - 1) ? Mptr[(t + 1) * NB + row] : 1.f;
        smask[row * NS + c] = f2bf(sq * mn);
      }
}

__global__ __launch_bounds__(256) void k5_bpri(
    const float* __restrict__ ball, const u16* __restrict__ wbpri,
    const float* __restrict__ b_bpri, u16* __restrict__ hpri, int tc) {
  const int l = threadIdx.x & 63, r16 = l & 15, kq = l >> 4;
  const int wid = threadIdx.x >> 6;
  const int bm = blockIdx.x & 63, bn = blockIdx.x >> 6;
  const int row0 = bm * 64 + (wid >> 1) * 32;
  const int col0 = bn * 64 + (wid & 1) * 32;
  f32x4 acc[2][2]; ZACC(acc);
  const float* Ab = ball + (size_t)tc * 4194304;
  const float* A0 = Ab + (size_t)(row0 + r16) * NBEL + kq * 8;
  const float* A1 = A0 + 16 * NBEL;
  const u16* B0 = wbpri + (size_t)(col0 + r16) * NBEL + kq * 8;
  const u16* B1 = B0 + 16 * NBEL;
  for (int k = 0; k < NBEL; k += 32) {
    bf16x8 a0 = cvt8(A0 + k), a1 = cvt8(A1 + k);
    bf16x8 b0 = ld8bf(B0 + k), b1 = ld8bf(B1 + k);
    Q4(acc, a0, a1, b0, b1);
  }
#pragma unroll
  for (int i = 0; i < 2; ++i)
#pragma unroll
    for (int j = 0; j < 2; ++j)
#pragma unroll
      for (int q = 0; q < 4; ++q) {
        const int row = row0 + i * 16 + kq * 4 + q;
        const int col = col0 + j * 16 + r16;
        const float v = acc[i][j][q] + b_bpri[col];
        hpri[(size_t)row * NBEL + col] = f2bf(fmaxf(v, 0.f));
      }
}

__global__ __launch_bounds__(256) void k6_spri(
    const u16* __restrict__ hpri, const u16* __restrict__ wspri,
    const float* __restrict__ b_spri, const float* __restrict__ npri,
    float* __restrict__ out, int tc) {
  const int l = threadIdx.x & 63, r16 = l & 15, kq = l >> 4;
  const int wid = threadIdx.x >> 6;
  const int bm = blockIdx.x & 63, bn = blockIdx.x >> 6;
  const int row0 = bm * 64 + (wid >> 1) * 32;
  const int c0 = bn * 64 + (wid & 1) * 32;
  f32x4 am[2][2], ah[2][2];
  ZACC(am); ZACC(ah);
  const u16* A0 = hpri + (size_t)(row0 + r16) * NBEL + kq * 8;
  const u16* A1 = A0 + 16 * NBEL;
  const u16* Bm0 = wspri + (size_t)(c0 + r16) * NBEL + kq * 8;
  const u16* Bm1 = Bm0 + 16 * NBEL;
  const u16* Bh0 = wspri + (size_t)(c0 + 256 + r16) * NBEL + kq * 8;
  const u16* Bh1 = Bh0 + 16 * NBEL;
  for (int k = 0; k < NBEL; k += 32) {
    bf16x8 a0 = ld8bf(A0 + k), a1 = ld8bf(A1 + k);
    bf16x8 m0 = ld8bf(Bm0 + k), m1 = ld8bf(Bm1 + k);
    Q4(am, a0, a1, m0, m1);
    bf16x8 h0 = ld8bf(Bh0 + k), h1 = ld8bf(Bh1 + k);
    Q4(ah, a0, a1, h0, h1);
  }
#pragma unroll
  for (int i = 0; i < 2; ++i)
#pragma unroll
    for (int j = 0; j < 2; ++j)
#pragma unroll
      for (int q = 0; q < 4; ++q) {
        const int row = row0 + i * 16 + kq * 4 + q;
        const int c = c0 + j * 16 + r16;
        const size_t rowg = (size_t)tc * 4096 + row;
        const size_t idx = rowg * NS + c;
        const float mu = am[i][j][q] + b_spri[c];
        const float hp = ah[i][j][q] + b_spri[c + 256];
        const float sd = softplus_(hp) + 0.1f;
        out[OUT_SPRI + idx] = mu + sd * npri[idx];
        out[OUT_MUPRI + idx] = mu;
        out[OUT_STDPRI + idx] = sd;
      }
}

extern "C" void kernel_launch(void* const* d_in, const int* in_sizes, int n_in,
                              void* d_out, int out_size, void* d_ws, size_t ws_size,
                              hipStream_t stream) {
  const float* s0 = (const float*)d_in[0];
  const float* Af = (const float*)d_in[1];
  const float* b0 = (const float*)d_in[2];
  const float* Of = (const float*)d_in[3];
  const float* Mp = (const float*)d_in[4];
  const float* npri = (const float*)d_in[5];
  const float* npos = (const float*)d_in[6];
  const float* Wsa = (const float*)d_in[7];
  const float* bsa = (const float*)d_in[8];
  const float* Wih = (const float*)d_in[9];
  const float* bih = (const float*)d_in[10];
  const float* Whh = (const float*)d_in[11];
  const float* bhh = (const float*)d_in[12];
  const float* Wbpri = (const float*)d_in[13];
  const float* bbpri = (const float*)d_in[14];
  const float* Wspri = (const float*)d_in[15];
  const float* bspri = (const float*)d_in[16];
  const float* Wbpos = (const float*)d_in[17];
  const float* bbpos = (const float*)d_in[18];
  const float* Wspos = (const float*)d_in[19];
  const float* bspos = (const float*)d_in[20];

  float* out = (float*)d_out;
  char* ws = (char*)d_ws;
  u16* wbase   = (u16*)ws;
  u16* wsa_b   = wbase;
  u16* wih_b   = wbase + 327680;
  u16* whh_b   = wbase + 3473408;
  u16* wbpri_b = wbase + 6619136;
  u16* wspri_b = wbase + 7667712;
  u16* wbpos_b = wbase + 8192000;
  u16* wspos_b = wbase + 10289152;
  u16*   smask = (u16*)  (ws + 21626880);
  u16*   bbf0  = (u16*)  (ws + 21889024);
  float* hf    = (float*)(ws + 22937600);
  u16*   xbf   = (u16*)  (ws + 25034752);
  float* gh    = (float*)(ws + 26083328);
  u16*   hbbf  = (u16*)  (ws + 32374784);
  u16*   hpri  = (u16*)  (ws + 33423360);  // fallback: 8 MB; coop uses first 1 MB
  u16*   bbf1  = (u16*)  (ws + 33423360 + 1048576);  // coop-only, overlaps fallback hpri tail
  // ws end: 41,811,968 bytes (same as round-2)

  RP p;
  p.Af = Af; p.Of = Of; p.Mp = Mp; p.npri = npri; p.npos = npos;
  p.bsa = bsa; p.bih = bih; p.bhh = bhh; p.bbpri = bbpri; p.bspri = bspri;
  p.bbpos = bbpos; p.bspos = bspos;
  p.s0 = s0; p.b0 = b0;
  p.Wsa = Wsa; p.Wih = Wih; p.Whh = Whh; p.Wbpri = Wbpri; p.Wspri = Wspri;
  p.Wbpos = Wbpos; p.Wspos = Wspos;
  p.out = out; p.hf = hf; p.gh = gh;
  p.wbase = wbase; p.smask = smask; p.bbf0 = bbf0; p.bbf1 = bbf1;
  p.xbf = xbf; p.hbbf = hbbf; p.hpri = hpri;

  void* args[] = {(void*)&p};
  hipError_t err = hipLaunchCooperativeKernel(
      reinterpret_cast<const void*>(&rssm_fused), dim3(512), dim3(256),
      args, 0, stream);
  if (err == hipSuccess) return;

  // -------- fallback: proven multi-kernel path --------
  cvt_weights_k<<<2048, 256, 0, stream>>>(Wsa, Wih, Whh, Wbpri, Wspri, Wbpos,
                                          Wspos, wbase);
  init_carry_k<<<2048, 256, 0, stream>>>(s0, b0, Mp, smask, bbf0, hf);
  for (int t = 0; t < NT; ++t) {
    k1_x_gh<<<512, 256, 0, stream>>>(smask, Af, wsa_b, bsa, bbf0, whh_b, bhh,
                                     xbf, gh, t);
    k2_gi_gru<<<128, 256, 0, stream>>>(xbf, wih_b, bih, gh, hf, bbf0, out, t);
    k3_hb<<<128, 256, 0, stream>>>(bbf0, Of, wbpos_b, bbpos, hbbf, t);
    k4_spos<<<32, 256, 0, stream>>>(hbbf, wspos_b, bspos, npos, Mp, out, smask, t);
  }
  for (int tc = 0; tc < 8; ++tc) {
    k5_bpri<<<1024, 256, 0, stream>>>(out + OUT_B, wbpri_b, bbpri, hpri, tc);
    k6_spri<<<256, 256, 0, stream>>>(hpri, wspri_b, bspri, npri, out, tc);
  }
}

// Round 4
// 10402.152 us; speedup vs baseline: 3.8308x; 3.8308x over previous
//
#include <hip/hip_runtime.h>
#include <hip/hip_bf16.h>
#include <math.h>

typedef short bf16x8 __attribute__((ext_vector_type(8)));
typedef float f32x4 __attribute__((ext_vector_type(4)));
typedef unsigned short u16;

#define NT 64
#define NB 512
#define NS 256
#define NA 64
#define NBEL 1024

// d_out element offsets (f32 elements)
#define OUT_B      0
#define OUT_SPRI   33554432
#define OUT_MUPRI  41943040
#define OUT_STDPRI 50331648
#define OUT_SPOS   58720256
#define OUT_MUPOS  67108864
#define OUT_STDPOS 75497472

__device__ __forceinline__ f32x4 mfma16(bf16x8 a, bf16x8 b, f32x4 c) {
  return __builtin_amdgcn_mfma_f32_16x16x32_bf16(a, b, c, 0, 0, 0);
}

__device__ __forceinline__ u16 f2bf(float f) {
  union { float f; unsigned u; } v; v.f = f;
  return (u16)((v.u + 0x7FFFu + ((v.u >> 16) & 1u)) >> 16);
}

__device__ __forceinline__ bf16x8 ld8bf(const u16* p) { return *(const bf16x8*)p; }

__device__ __forceinline__ bf16x8 cvt8(const float* p) {
  const float4 lo = *(const float4*)p;
  const float4 hi = *(const float4*)(p + 4);
  bf16x8 v;
  v[0] = (short)f2bf(lo.x); v[1] = (short)f2bf(lo.y);
  v[2] = (short)f2bf(lo.z); v[3] = (short)f2bf(lo.w);
  v[4] = (short)f2bf(hi.x); v[5] = (short)f2bf(hi.y);
  v[6] = (short)f2bf(hi.z); v[7] = (short)f2bf(hi.w);
  return v;
}

__device__ __forceinline__ float sigm(float x) { return 1.f / (1.f + __expf(-x)); }
__device__ __forceinline__ float softplus_(float x) {
  if (x > 20.f) return x;
  return log1pf(__expf(x));
}

#define ZACC(acc) { acc[0][0] = (f32x4){0.f,0.f,0.f,0.f}; acc[0][1] = (f32x4){0.f,0.f,0.f,0.f}; \
                    acc[1][0] = (f32x4){0.f,0.f,0.f,0.f}; acc[1][1] = (f32x4){0.f,0.f,0.f,0.f}; }

#define Q4(acc, a0v, a1v, b0v, b1v) \
  acc[0][0] = mfma16(a0v, b0v, acc[0][0]); \
  acc[0][1] = mfma16(a0v, b1v, acc[0][1]); \
  acc[1][0] = mfma16(a1v, b0v, acc[1][0]); \
  acc[1][1] = mfma16(a1v, b1v, acc[1][1]);

// -------- P0: weights f32 -> bf16 into ws --------
__global__ __launch_bounds__(256) void cvt_weights_k(
    const float* __restrict__ wsa, const float* __restrict__ wih,
    const float* __restrict__ whh, const float* __restrict__ wbpri,
    const float* __restrict__ wspri, const float* __restrict__ wbpos,
    const float* __restrict__ wspos, u16* __restrict__ dst) {
  const int S0 = 327680;
  const int S1 = S0 + 3145728;
  const int S2 = S1 + 3145728;
  const int S3 = S2 + 1048576;
  const int S4 = S3 + 524288;
  const int S5 = S4 + 2097152;
  const int S6 = S5 + 524288;  // 10,813,440 elements
  for (int i = blockIdx.x * blockDim.x + threadIdx.x; i < S6;
       i += gridDim.x * blockDim.x) {
    float v;
    if (i < S0) v = wsa[i];
    else if (i < S1) v = wih[i - S0];
    else if (i < S2) v = whh[i - S1];
    else if (i < S3) v = wbpri[i - S2];
    else if (i < S4) v = wspri[i - S3];
    else if (i < S5) v = wbpos[i - S4];
    else v = wspos[i - S5];
    dst[i] = f2bf(v);
  }
}

// -------- P1: init carries --------
__global__ __launch_bounds__(256) void init_carry_k(
    const float* __restrict__ s0, const float* __restrict__ b0,
    const float* __restrict__ Mptr, u16* __restrict__ smask,
    u16* __restrict__ bbf0, float* __restrict__ hf) {
  for (int i = blockIdx.x * blockDim.x + threadIdx.x; i < NB * NBEL;
       i += gridDim.x * blockDim.x) {
    float b = b0[i];
    bbf0[i] = f2bf(b);
    hf[i] = b;
    if (i < NB * NS) {
      int row = i >> 8;
      smask[i] = f2bf(s0[i] * Mptr[row]);
    }
  }
}

// ======================= device GEMM pieces =======================
// All use 4 waves/block (2x2 of 32x32-wave tiles) => 64x64 block tile,
// except spri/spos (mu+std fused, 2 acc sets).

// x = relu([s*m | a_t] @ Wsa^T + b_sa) : 128 blocks (8 x 16)
__device__ __forceinline__ void dev_x(
    int g, int wid, int r16, int kq, int t,
    const u16* __restrict__ smask, const float* __restrict__ Af,
    const u16* __restrict__ wsa, const float* __restrict__ bsa,
    u16* __restrict__ xbf) {
  const int bm = g >> 4, bn = g & 15;  // bn%8 -> XCD column affinity
  const int row0 = bm * 64 + (wid >> 1) * 32;
  const int col0 = bn * 64 + (wid & 1) * 32;
  f32x4 acc[2][2]; ZACC(acc);
  {
    const u16* A0 = smask + (row0 + r16) * NS + kq * 8;
    const u16* A1 = A0 + 16 * NS;
    const u16* B0 = wsa + (size_t)(col0 + r16) * 320 + kq * 8;
    const u16* B1 = B0 + 16 * 320;
#pragma unroll
    for (int k = 0; k < NS; k += 32) {
      bf16x8 a0 = ld8bf(A0 + k), a1 = ld8bf(A1 + k);
      bf16x8 b0 = ld8bf(B0 + k), b1 = ld8bf(B1 + k);
      Q4(acc, a0, a1, b0, b1);
    }
  }
  {
    const float* A0 = Af + (size_t)t * (NB * NA) + (row0 + r16) * NA + kq * 8;
    const float* A1 = A0 + 16 * NA;
    const u16* B0 = wsa + (size_t)(col0 + r16) * 320 + 256 + kq * 8;
    const u16* B1 = B0 + 16 * 320;
#pragma unroll
    for (int k = 0; k < NA; k += 32) {
      bf16x8 a0 = cvt8(A0 + k), a1 = cvt8(A1 + k);
      bf16x8 b0 = ld8bf(B0 + k), b1 = ld8bf(B1 + k);
      Q4(acc, a0, a1, b0, b1);
    }
  }
#pragma unroll
  for (int i = 0; i < 2; ++i)
#pragma unroll
    for (int j = 0; j < 2; ++j)
#pragma unroll
      for (int q = 0; q < 4; ++q) {
        const int row = row0 + i * 16 + kq * 4 + q;
        const int col = col0 + j * 16 + r16;
        xbf[row * NBEL + col] = f2bf(fmaxf(acc[i][j][q] + bsa[col], 0.f));
      }
}

// hbO = o_t @ WbposO^T (f32 partial, no bias) : 128 blocks (8 x 16)
__device__ __forceinline__ void dev_hbO(
    int g, int wid, int r16, int kq, int t,
    const float* __restrict__ Of, const u16* __restrict__ wbpos,
    float* __restrict__ hbO) {
  const int bm = g >> 4, bn = g & 15;
  const int row0 = bm * 64 + (wid >> 1) * 32;
  const int col0 = bn * 64 + (wid & 1) * 32;
  f32x4 acc[2][2]; ZACC(acc);
  const float* A0 = Of + (size_t)t * (NB * NBEL) + (row0 + r16) * NBEL + kq * 8;
  const float* A1 = A0 + 16 * NBEL;
  const u16* B0 = wbpos + (size_t)(col0 + r16) * 2048 + 1024 + kq * 8;
  const u16* B1 = B0 + 16 * 2048;
  for (int k = 0; k < NBEL; k += 32) {
    bf16x8 a0 = cvt8(A0 + k), a1 = cvt8(A1 + k);
    bf16x8 b0 = ld8bf(B0 + k), b1 = ld8bf(B1 + k);
    Q4(acc, a0, a1, b0, b1);
  }
#pragma unroll
  for (int i = 0; i < 2; ++i)
#pragma unroll
    for (int j = 0; j < 2; ++j)
#pragma unroll
      for (int q = 0; q < 4; ++q) {
        const int row = row0 + i * 16 + kq * 4 + q;
        const int col = col0 + j * 16 + r16;
        hbO[row * NBEL + col] = acc[i][j][q];
      }
}

// gh = b_prev @ Whh^T + b_hh (f32) : 384 blocks (8 x 48)
__device__ __forceinline__ void dev_gh(
    int g, int wid, int r16, int kq,
    const u16* __restrict__ bsrc, const u16* __restrict__ whh,
    const float* __restrict__ bhh, float* __restrict__ gh) {
  const int bm = g / 48, bn = g % 48;  // 48%8==0 -> column affinity
  const int row0 = bm * 64 + (wid >> 1) * 32;
  const int col0 = bn * 64 + (wid & 1) * 32;
  f32x4 acc[2][2]; ZACC(acc);
  const u16* A0 = bsrc + (row0 + r16) * NBEL + kq * 8;
  const u16* A1 = A0 + 16 * NBEL;
  const u16* B0 = whh + (size_t)(col0 + r16) * NBEL + kq * 8;
  const u16* B1 = B0 + 16 * NBEL;
  for (int k = 0; k < NBEL; k += 32) {
    bf16x8 a0 = ld8bf(A0 + k), a1 = ld8bf(A1 + k);
    bf16x8 b0 = ld8bf(B0 + k), b1 = ld8bf(B1 + k);
    Q4(acc, a0, a1, b0, b1);
  }
#pragma unroll
  for (int i = 0; i < 2; ++i)
#pragma unroll
    for (int j = 0; j < 2; ++j)
#pragma unroll
      for (int q = 0; q < 4; ++q) {
        const int row = row0 + i * 16 + kq * 4 + q;
        const int col = col0 + j * 16 + r16;
        gh[row * 3072 + col] = acc[i][j][q] + bhh[col];
      }
}

// gi (3 gates) + GRU fuse -> bnew : 128 blocks (8 x 16)
__device__ __forceinline__ void dev_gi_gru(
    int g, int wid, int r16, int kq, int t,
    const u16* __restrict__ xbf, const u16* __restrict__ wih,
    const float* __restrict__ bih, const float* __restrict__ gh,
    float* __restrict__ hf, u16* __restrict__ bcur,
    float* __restrict__ out) {
  const int bm = g >> 4, bn = g & 15;
  const int row0 = bm * 64 + (wid >> 1) * 32;
  const int col0 = bn * 64 + (wid & 1) * 32;
  f32x4 ar[2][2], az[2][2], an[2][2];
  ZACC(ar); ZACC(az); ZACC(an);
  const u16* A0 = xbf + (row0 + r16) * NBEL + kq * 8;
  const u16* A1 = A0 + 16 * NBEL;
  const u16* Br0 = wih + (size_t)(col0 + r16) * NBEL + kq * 8;
  const u16* Br1 = Br0 + 16 * NBEL;
  const u16* Bz0 = wih + (size_t)(col0 + 1024 + r16) * NBEL + kq * 8;
  const u16* Bz1 = Bz0 + 16 * NBEL;
  const u16* Bn0 = wih + (size_t)(col0 + 2048 + r16) * NBEL + kq * 8;
  const u16* Bn1 = Bn0 + 16 * NBEL;
  for (int k = 0; k < NBEL; k += 32) {
    bf16x8 a0 = ld8bf(A0 + k), a1 = ld8bf(A1 + k);
    bf16x8 b0 = ld8bf(Br0 + k), b1 = ld8bf(Br1 + k);
    Q4(ar, a0, a1, b0, b1);
    bf16x8 c0 = ld8bf(Bz0 + k), c1 = ld8bf(Bz1 + k);
    Q4(az, a0, a1, c0, c1);
    bf16x8 d0 = ld8bf(Bn0 + k), d1 = ld8bf(Bn1 + k);
    Q4(an, a0, a1, d0, d1);
  }
#pragma unroll
  for (int i = 0; i < 2; ++i)
#pragma unroll
    for (int j = 0; j < 2; ++j)
#pragma unroll
      for (int q = 0; q < 4; ++q) {
        const int row = row0 + i * 16 + kq * 4 + q;
        const int c = col0 + j * 16 + r16;
        const float gir = ar[i][j][q] + bih[c];
        const float giz = az[i][j][q] + bih[c + 1024];
        const float gin = an[i][j][q] + bih[c + 2048];
        const float* ghrow = gh + row * 3072;
        const float r = sigm(gir + ghrow[c]);
        const float z = sigm(giz + ghrow[c + 1024]);
        const float n = tanhf(gin + r * ghrow[c + 2048]);
        const float h = hf[row * NBEL + c];
        const float bnew = (1.f - z) * n + z * h;
        hf[row * NBEL + c] = bnew;
        bcur[row * NBEL + c] = f2bf(bnew);
        out[OUT_B + (size_t)t * (NB * NBEL) + row * NBEL + c] = bnew;
      }
}

// hpri = relu(b_prev @ Wbpri^T + b) : 128 blocks (8 x 16)
__device__ __forceinline__ void dev_bpri(
    int g, int wid, int r16, int kq,
    const u16* __restrict__ bsrc, const u16* __restrict__ wbpri,
    const float* __restrict__ bbpri, u16* __restrict__ hpri) {
  const int bm = g >> 4, bn = g & 15;
  const int row0 = bm * 64 + (wid >> 1) * 32;
  const int col0 = bn * 64 + (wid & 1) * 32;
  f32x4 acc[2][2]; ZACC(acc);
  const u16* A0 = bsrc + (row0 + r16) * NBEL + kq * 8;
  const u16* A1 = A0 + 16 * NBEL;
  const u16* B0 = wbpri + (size_t)(col0 + r16) * NBEL + kq * 8;
  const u16* B1 = B0 + 16 * NBEL;
  for (int k = 0; k < NBEL; k += 32) {
    bf16x8 a0 = ld8bf(A0 + k), a1 = ld8bf(A1 + k);
    bf16x8 b0 = ld8bf(B0 + k), b1 = ld8bf(B1 + k);
    Q4(acc, a0, a1, b0, b1);
  }
#pragma unroll
  for (int i = 0; i < 2; ++i)
#pragma unroll
    for (int j = 0; j < 2; ++j)
#pragma unroll
      for (int q = 0; q < 4; ++q) {
        const int row = row0 + i * 16 + kq * 4 + q;
        const int col = col0 + j * 16 + r16;
        hpri[row * NBEL + col] = f2bf(fmaxf(acc[i][j][q] + bbpri[col], 0.f));
      }
}

// hb = relu(bnew @ WbposB^T + hbO + bias) : 128 blocks (8 x 16)
__device__ __forceinline__ void dev_hbB(
    int g, int wid, int r16, int kq,
    const u16* __restrict__ bcur, const u16* __restrict__ wbpos,
    const float* __restrict__ bbpos, const float* __restrict__ hbO,
    u16* __restrict__ hbbf) {
  const int bm = g >> 4, bn = g & 15;
  const int row0 = bm * 64 + (wid >> 1) * 32;
  const int col0 = bn * 64 + (wid & 1) * 32;
  f32x4 acc[2][2]; ZACC(acc);
  const u16* A0 = bcur + (row0 + r16) * NBEL + kq * 8;
  const u16* A1 = A0 + 16 * NBEL;
  const u16* B0 = wbpos + (size_t)(col0 + r16) * 2048 + kq * 8;
  const u16* B1 = B0 + 16 * 2048;
  for (int k = 0; k < NBEL; k += 32) {
    bf16x8 a0 = ld8bf(A0 + k), a1 = ld8bf(A1 + k);
    bf16x8 b0 = ld8bf(B0 + k), b1 = ld8bf(B1 + k);
    Q4(acc, a0, a1, b0, b1);
  }
#pragma unroll
  for (int i = 0; i < 2; ++i)
#pragma unroll
    for (int j = 0; j < 2; ++j)
#pragma unroll
      for (int q = 0; q < 4; ++q) {
        const int row = row0 + i * 16 + kq * 4 + q;
        const int col = col0 + j * 16 + r16;
        const float v = acc[i][j][q] + hbO[row * NBEL + col] + bbpos[col];
        hbbf[row * NBEL + col] = f2bf(fmaxf(v, 0.f));
      }
}

// spri head + sample @ step tt : 32 blocks (8 x 4)
__device__ __forceinline__ void dev_spri(
    int g, int wid, int r16, int kq, int tt,
    const u16* __restrict__ hpri, const u16* __restrict__ wspri,
    const float* __restrict__ bspri, const float* __restrict__ npri,
    float* __restrict__ out) {
  const int bm = g >> 2, bn = g & 3;
  const int row0 = bm * 64 + (wid >> 1) * 32;
  const int c0 = bn * 64 + (wid & 1) * 32;
  f32x4 am[2][2], ah[2][2];
  ZACC(am); ZACC(ah);
  const u16* A0 = hpri + (row0 + r16) * NBEL + kq * 8;
  const u16* A1 = A0 + 16 * NBEL;
  const u16* Bm0 = wspri + (size_t)(c0 + r16) * NBEL + kq * 8;
  const u16* Bm1 = Bm0 + 16 * NBEL;
  const u16* Bh0 = wspri + (size_t)(c0 + 256 + r16) * NBEL + kq * 8;
  const u16* Bh1 = Bh0 + 16 * NBEL;
  for (int k = 0; k < NBEL; k += 32) {
    bf16x8 a0 = ld8bf(A0 + k), a1 = ld8bf(A1 + k);
    bf16x8 m0 = ld8bf(Bm0 + k), m1 = ld8bf(Bm1 + k);
    Q4(am, a0, a1, m0, m1);
    bf16x8 h0 = ld8bf(Bh0 + k), h1 = ld8bf(Bh1 + k);
    Q4(ah, a0, a1, h0, h1);
  }
#pragma unroll
  for (int i = 0; i < 2; ++i)
#pragma unroll
    for (int j = 0; j < 2; ++j)
#pragma unroll
      for (int q = 0; q < 4; ++q) {
        const int row = row0 + i * 16 + kq * 4 + q;
        const int c = c0 + j * 16 + r16;
        const size_t idx = (size_t)tt * (NB * NS) + row * NS + c;
        const float mu = am[i][j][q] + bspri[c];
        const float hp = ah[i][j][q] + bspri[c + 256];
        const float sd = softplus_(hp) + 0.1f;
        out[OUT_SPRI + idx] = mu + sd * npri[idx];
        out[OUT_MUPRI + idx] = mu;
        out[OUT_STDPRI + idx] = sd;
      }
}

// spos head + sample + next-step mask : 32 blocks (8 x 4)
__device__ __forceinline__ void dev_spos(
    int g, int wid, int r16, int kq, int t,
    const u16* __restrict__ hbbf, const u16* __restrict__ wspos,
    const float* __restrict__ bspos, const float* __restrict__ npos,
    const float* __restrict__ Mptr, float* __restrict__ out,
    u16* __restrict__ smask) {
  const int bm = g >> 2, bn = g & 3;
  const int row0 = bm * 64 + (wid >> 1) * 32;
  const int c0 = bn * 64 + (wid & 1) * 32;
  f32x4 am[2][2], ah[2][2];
  ZACC(am); ZACC(ah);
  const u16* A0 = hbbf + (row0 + r16) * NBEL + kq * 8;
  const u16* A1 = A0 + 16 * NBEL;
  const u16* Bm0 = wspos + (size_t)(c0 + r16) * NBEL + kq * 8;
  const u16* Bm1 = Bm0 + 16 * NBEL;
  const u16* Bh0 = wspos + (size_t)(c0 + 256 + r16) * NBEL + kq * 8;
  const u16* Bh1 = Bh0 + 16 * NBEL;
  for (int k = 0; k < NBEL; k += 32) {
    bf16x8 a0 = ld8bf(A0 + k), a1 = ld8bf(A1 + k);
    bf16x8 m0 = ld8bf(Bm0 + k), m1 = ld8bf(Bm1 + k);
    Q4(am, a0, a1, m0, m1);
    bf16x8 h0 = ld8bf(Bh0 + k), h1 = ld8bf(Bh1 + k);
    Q4(ah, a0, a1, h0, h1);
  }
#pragma unroll
  for (int i = 0; i < 2; ++i)
#pragma unroll
    for (int j = 0; j < 2; ++j)
#pragma unroll
      for (int q = 0; q < 4; ++q) {
        const int row = row0 + i * 16 + kq * 4 + q;
        const int c = c0 + j * 16 + r16;
        const float mu = am[i][j][q] + bspos[c];
        const float hq = ah[i][j][q] + bspos[c + 256];
        const float sd = softplus_(hq) + 0.1f;
        const size_t idx = (size_t)t * (NB * NS) + row * NS + c;
        const float sq = mu + sd * npos[idx];
        out[OUT_SPOS + idx] = sq;
        out[OUT_MUPOS + idx] = mu;
        out[OUT_STDPOS + idx] = sd;
        const float mn = (t < NT - 1) ? Mptr[(t + 1) * NB + row] : 1.f;
        smask[row * NS + c] = f2bf(sq * mn);
      }
}

// ======================= top-level kernels =======================
__global__ __launch_bounds__(256) void kp_gh0(
    const u16* bbf0, const u16* whh, const float* bhh, float* gh) {
  const int l = threadIdx.x & 63, r16 = l & 15, kq = l >> 4;
  const int wid = threadIdx.x >> 6;
  dev_gh(blockIdx.x, wid, r16, kq, bbf0, whh, bhh, gh);
}

// kA: x(t) [0..127] | hbO(t) [128..255]
__global__ __launch_bounds__(256) void kA(
    const u16* smask, const float* Af, const u16* wsa, const float* bsa,
    u16* xbf, const float* Of, const u16* wbpos, float* hbO, int t) {
  const int l = threadIdx.x & 63, r16 = l & 15, kq = l >> 4;
  const int wid = threadIdx.x >> 6;
  if (blockIdx.x < 128)
    dev_x(blockIdx.x, wid, r16, kq, t, smask, Af, wsa, bsa, xbf);
  else
    dev_hbO(blockIdx.x - 128, wid, r16, kq, t, Of, wbpos, hbO);
}

// kB: gi+GRU(t) [0..127, if t<NT] | bpri(t-1) [128..255, if t>=1]
__global__ __launch_bounds__(256) void kB(
    const u16* xbf, const u16* wih, const float* bih, const float* gh,
    float* hf, u16* bcur, float* out,
    const u16* bprev, const u16* wbpri, const float* bbpri, u16* hpri, int t) {
  const int l = threadIdx.x & 63, r16 = l & 15, kq = l >> 4;
  const int wid = threadIdx.x >> 6;
  if (blockIdx.x < 128) {
    if (t < NT)
      dev_gi_gru(blockIdx.x, wid, r16, kq, t, xbf, wih, bih, gh, hf, bcur, out);
  } else {
    if (t >= 1)
      dev_bpri(blockIdx.x - 128, wid, r16, kq, bprev, wbpri, bbpri, hpri);
  }
}

// kC: hbB(t) [0..127, t<NT] | gh(t+1) [128..511, t+1<NT] | spri(t-1) [512..543, t>=1]
__global__ __launch_bounds__(256) void kC(
    const u16* bcur, const u16* wbpos, const float* bbpos, const float* hbO,
    u16* hbbf, const u16* whh, const float* bhh, float* gh,
    const u16* hpri, const u16* wspri, const float* bspri, const float* npri,
    float* out, int t) {
  const int l = threadIdx.x & 63, r16 = l & 15, kq = l >> 4;
  const int wid = threadIdx.x >> 6;
  if (blockIdx.x < 128) {
    if (t < NT)
      dev_hbB(blockIdx.x, wid, r16, kq, bcur, wbpos, bbpos, hbO, hbbf);
  } else if (blockIdx.x < 512) {
    if (t + 1 < NT)
      dev_gh(blockIdx.x - 128, wid, r16, kq, bcur, whh, bhh, gh);
  } else {
    if (t >= 1)
      dev_spri(blockIdx.x - 512, wid, r16, kq, t - 1, hpri, wspri, bspri, npri, out);
  }
}

// kD: spos(t) [32 blocks]
__global__ __launch_bounds__(256) void kD(
    const u16* hbbf, const u16* wspos, const float* bspos, const float* npos,
    const float* Mptr, float* out, u16* smask, int t) {
  const int l = threadIdx.x & 63, r16 = l & 15, kq = l >> 4;
  const int wid = threadIdx.x >> 6;
  dev_spos(blockIdx.x, wid, r16, kq, t, hbbf, wspos, bspos, npos, Mptr, out, smask);
}

extern "C" void kernel_launch(void* const* d_in, const int* in_sizes, int n_in,
                              void* d_out, int out_size, void* d_ws, size_t ws_size,
                              hipStream_t stream) {
  const float* s0 = (const float*)d_in[0];
  const float* Af = (const float*)d_in[1];
  const float* b0 = (const float*)d_in[2];
  const float* Of = (const float*)d_in[3];
  const float* Mp = (const float*)d_in[4];
  const float* npri = (const float*)d_in[5];
  const float* npos = (const float*)d_in[6];
  const float* Wsa = (const float*)d_in[7];
  const float* bsa = (const float*)d_in[8];
  const float* Wih = (const float*)d_in[9];
  const float* bih = (const float*)d_in[10];
  const float* Whh = (const float*)d_in[11];
  const float* bhh = (const float*)d_in[12];
  const float* Wbpri = (const float*)d_in[13];
  const float* bbpri = (const float*)d_in[14];
  const float* Wspri = (const float*)d_in[15];
  const float* bspri = (const float*)d_in[16];
  const float* Wbpos = (const float*)d_in[17];
  const float* bbpos = (const float*)d_in[18];
  const float* Wspos = (const float*)d_in[19];
  const float* bspos = (const float*)d_in[20];

  float* out = (float*)d_out;
  char* ws = (char*)d_ws;
  u16* wbase   = (u16*)ws;
  u16* wsa_b   = wbase;
  u16* wih_b   = wbase + 327680;
  u16* whh_b   = wbase + 3473408;
  u16* wbpri_b = wbase + 6619136;
  u16* wspri_b = wbase + 7667712;
  u16* wbpos_b = wbase + 8192000;
  u16* wspos_b = wbase + 10289152;
  // weights end at byte 21,626,880
  u16*   smask = (u16*)  (ws + 21626880);  // [512,256]  bf16  256KB
  u16*   bbf0  = (u16*)  (ws + 21889024);  // [512,1024] bf16  1MB
  u16*   bbf1  = (u16*)  (ws + 22937600);  // [512,1024] bf16  1MB
  float* hf    = (float*)(ws + 23986176);  // [512,1024] f32   2MB
  u16*   xbf   = (u16*)  (ws + 26083328);  // [512,1024] bf16  1MB
  float* gh    = (float*)(ws + 27131904);  // [512,3072] f32   6MB
  float* hbO   = (float*)(ws + 33423360);  // [512,1024] f32   2MB
  u16*   hbbf  = (u16*)  (ws + 35520512);  // [512,1024] bf16  1MB
  u16*   hpri  = (u16*)  (ws + 36569088);  // [512,1024] bf16  1MB
  // ws end: 37,617,664 bytes

  cvt_weights_k<<<2048, 256, 0, stream>>>(Wsa, Wih, Whh, Wbpri, Wspri, Wbpos,
                                          Wspos, wbase);
  init_carry_k<<<2048, 256, 0, stream>>>(s0, b0, Mp, smask, bbf0, hf);
  kp_gh0<<<384, 256, 0, stream>>>(bbf0, whh_b, bhh, gh);

  for (int t = 0; t < NT; ++t) {
    const u16* bprev = (t & 1) ? bbf1 : bbf0;
    u16* bcur = (t & 1) ? bbf0 : bbf1;
    kA<<<256, 256, 0, stream>>>(smask, Af, wsa_b, bsa, xbf, Of, wbpos_b, hbO, t);
    kB<<<256, 256, 0, stream>>>(xbf, wih_b, bih, gh, hf, bcur, out,
                                bprev, wbpri_b, bbpri, hpri, t);
    kC<<<544, 256, 0, stream>>>(bcur, wbpos_b, bbpos, hbO, hbbf,
                                whh_b, bhh, gh,
                                hpri, wspri_b, bspri, npri, out, t);
    kD<<<32, 256, 0, stream>>>(hbbf, wspos_b, bspos, npos, Mp, out, smask, t);
  }
  // tail: bpri(63) then spri(63)
  {
    const int t = NT;
    const u16* bprev = (t & 1) ? bbf1 : bbf0;  // bnew(63)
    u16* bcur = (t & 1) ? bbf0 : bbf1;
    kB<<<256, 256, 0, stream>>>(xbf, wih_b, bih, gh, hf, bcur, out,
                                bprev, wbpri_b, bbpri, hpri, t);
    kC<<<544, 256, 0, stream>>>(bcur, wbpos_b, bbpos, hbO, hbbf,
                                whh_b, bhh, gh,
                                hpri, wspri_b, bspri, npri, out, t);
  }
}

// Round 5
// 10059.004 us; speedup vs baseline: 3.9615x; 1.0341x over previous
//
#include <hip/hip_runtime.h>
#include <hip/hip_bf16.h>
#include <math.h>

typedef short bf16x8 __attribute__((ext_vector_type(8)));
typedef float f32x4 __attribute__((ext_vector_type(4)));
typedef unsigned short u16;

#define NT 64
#define NB 512
#define NS 256
#define NA 64
#define NBEL 1024

// d_out element offsets (f32 elements)
#define OUT_B      0
#define OUT_SPRI   33554432
#define OUT_MUPRI  41943040
#define OUT_STDPRI 50331648
#define OUT_SPOS   58720256
#define OUT_MUPOS  67108864
#define OUT_STDPOS 75497472

__device__ __forceinline__ f32x4 mfma16(bf16x8 a, bf16x8 b, f32x4 c) {
  return __builtin_amdgcn_mfma_f32_16x16x32_bf16(a, b, c, 0, 0, 0);
}

__device__ __forceinline__ u16 f2bf(float f) {
  union { float f; unsigned u; } v; v.f = f;
  return (u16)((v.u + 0x7FFFu + ((v.u >> 16) & 1u)) >> 16);
}

__device__ __forceinline__ bf16x8 ld8bf(const u16* p) { return *(const bf16x8*)p; }

__device__ __forceinline__ bf16x8 cvt8(const float* p) {
  const float4 lo = *(const float4*)p;
  const float4 hi = *(const float4*)(p + 4);
  bf16x8 v;
  v[0] = (short)f2bf(lo.x); v[1] = (short)f2bf(lo.y);
  v[2] = (short)f2bf(lo.z); v[3] = (short)f2bf(lo.w);
  v[4] = (short)f2bf(hi.x); v[5] = (short)f2bf(hi.y);
  v[6] = (short)f2bf(hi.z); v[7] = (short)f2bf(hi.w);
  return v;
}

__device__ __forceinline__ float sigm(float x) { return 1.f / (1.f + __expf(-x)); }
__device__ __forceinline__ float softplus_(float x) {
  if (x > 20.f) return x;
  return log1pf(__expf(x));
}

#define ZACC(acc) { acc[0][0] = (f32x4){0.f,0.f,0.f,0.f}; acc[0][1] = (f32x4){0.f,0.f,0.f,0.f}; \
                    acc[1][0] = (f32x4){0.f,0.f,0.f,0.f}; acc[1][1] = (f32x4){0.f,0.f,0.f,0.f}; }

#define Q4(acc, a0v, a1v, b0v, b1v) \
  acc[0][0] = mfma16(a0v, b0v, acc[0][0]); \
  acc[0][1] = mfma16(a0v, b1v, acc[0][1]); \
  acc[1][0] = mfma16(a1v, b0v, acc[1][0]); \
  acc[1][1] = mfma16(a1v, b1v, acc[1][1]);

// K-split combine helpers: wave kh=1 writes its partial tile, wave kh=0 adds.
__device__ __forceinline__ void red_write(float* L, f32x4 (&acc)[2][2], int l) {
  const int base = l * 16;
#pragma unroll
  for (int i = 0; i < 2; ++i)
#pragma unroll
    for (int j = 0; j < 2; ++j)
#pragma unroll
      for (int q = 0; q < 4; ++q)
        L[base + (i * 2 + j) * 4 + q] = acc[i][j][q];
}
__device__ __forceinline__ void red_add(const float* L, f32x4 (&acc)[2][2], int l) {
  const int base = l * 16;
#pragma unroll
  for (int i = 0; i < 2; ++i)
#pragma unroll
    for (int j = 0; j < 2; ++j)
#pragma unroll
      for (int q = 0; q < 4; ++q)
        acc[i][j][q] += L[base + (i * 2 + j) * 4 + q];
}

// -------- P0: weights f32 -> bf16 into ws --------
__global__ __launch_bounds__(256) void cvt_weights_k(
    const float* __restrict__ wsa, const float* __restrict__ wih,
    const float* __restrict__ whh, const float* __restrict__ wbpri,
    const float* __restrict__ wspri, const float* __restrict__ wbpos,
    const float* __restrict__ wspos, u16* __restrict__ dst) {
  const int S0 = 327680;
  const int S1 = S0 + 3145728;
  const int S2 = S1 + 3145728;
  const int S3 = S2 + 1048576;
  const int S4 = S3 + 524288;
  const int S5 = S4 + 2097152;
  const int S6 = S5 + 524288;  // 10,813,440 elements
  for (int i = blockIdx.x * blockDim.x + threadIdx.x; i < S6;
       i += gridDim.x * blockDim.x) {
    float v;
    if (i < S0) v = wsa[i];
    else if (i < S1) v = wih[i - S0];
    else if (i < S2) v = whh[i - S1];
    else if (i < S3) v = wbpri[i - S2];
    else if (i < S4) v = wspri[i - S3];
    else if (i < S5) v = wbpos[i - S4];
    else v = wspos[i - S5];
    dst[i] = f2bf(v);
  }
}

// -------- P1: init carries --------
__global__ __launch_bounds__(256) void init_carry_k(
    const float* __restrict__ s0, const float* __restrict__ b0,
    const float* __restrict__ Mptr, u16* __restrict__ smask,
    u16* __restrict__ bbf0, float* __restrict__ hf) {
  for (int i = blockIdx.x * blockDim.x + threadIdx.x; i < NB * NBEL;
       i += gridDim.x * blockDim.x) {
    float b = b0[i];
    bbf0[i] = f2bf(b);
    hf[i] = b;
    if (i < NB * NS) {
      int row = i >> 8;
      smask[i] = f2bf(s0[i] * Mptr[row]);
    }
  }
}

// ======================= kA: x(t) [0..127] | hbO(t) [128..255] =======================
__global__ __launch_bounds__(512, 2) void kA(
    const u16* __restrict__ smask, const float* __restrict__ Af,
    const u16* __restrict__ wsa, const float* __restrict__ bsa,
    u16* __restrict__ xbf, const float* __restrict__ Of,
    const u16* __restrict__ wbpos, float* __restrict__ hbO, int t) {
  __shared__ float lred[4][1024];
  const int l = threadIdx.x & 63, r16 = l & 15, kq = l >> 4;
  const int wid8 = threadIdx.x >> 6;
  const int wid = wid8 & 3, kh = wid8 >> 2;
  if (blockIdx.x < 128) {
    // x = relu([smask | a_t] @ Wsa^T + bsa), K=320 split 160/160
    const int g = blockIdx.x, bm = g >> 4, bn = g & 15;
    const int row0 = bm * 64 + (wid >> 1) * 32;
    const int col0 = bn * 64 + (wid & 1) * 32;
    f32x4 acc[2][2]; ZACC(acc);
    const u16* A0 = smask + (row0 + r16) * NS + kq * 8;
    const u16* A1 = A0 + 16 * NS;
    const u16* B0 = wsa + (size_t)(col0 + r16) * 320 + kq * 8;
    const u16* B1 = B0 + 16 * 320;
    if (kh == 0) {
#pragma unroll
      for (int k = 0; k < 160; k += 32) {
        bf16x8 a0 = ld8bf(A0 + k), a1 = ld8bf(A1 + k);
        bf16x8 b0 = ld8bf(B0 + k), b1 = ld8bf(B1 + k);
        Q4(acc, a0, a1, b0, b1);
      }
    } else {
#pragma unroll
      for (int k = 160; k < 256; k += 32) {
        bf16x8 a0 = ld8bf(A0 + k), a1 = ld8bf(A1 + k);
        bf16x8 b0 = ld8bf(B0 + k), b1 = ld8bf(B1 + k);
        Q4(acc, a0, a1, b0, b1);
      }
      const float* F0 = Af + (size_t)t * (NB * NA) + (row0 + r16) * NA + kq * 8;
      const float* F1 = F0 + 16 * NA;
      const u16* C0 = wsa + (size_t)(col0 + r16) * 320 + 256 + kq * 8;
      const u16* C1 = C0 + 16 * 320;
#pragma unroll
      for (int k = 0; k < 64; k += 32) {
        bf16x8 a0 = cvt8(F0 + k), a1 = cvt8(F1 + k);
        bf16x8 b0 = ld8bf(C0 + k), b1 = ld8bf(C1 + k);
        Q4(acc, a0, a1, b0, b1);
      }
      red_write(lred[wid], acc, l);
    }
    __syncthreads();
    if (kh == 0) {
      red_add(lred[wid], acc, l);
#pragma unroll
      for (int i = 0; i < 2; ++i)
#pragma unroll
        for (int j = 0; j < 2; ++j)
#pragma unroll
          for (int q = 0; q < 4; ++q) {
            const int row = row0 + i * 16 + kq * 4 + q;
            const int col = col0 + j * 16 + r16;
            xbf[row * NBEL + col] = f2bf(fmaxf(acc[i][j][q] + bsa[col], 0.f));
          }
    }
  } else {
    // hbO = o_t @ WbposO^T (f32 partial), K=1024 split 512/512
    const int g = blockIdx.x - 128, bm = g >> 4, bn = g & 15;
    const int row0 = bm * 64 + (wid >> 1) * 32;
    const int col0 = bn * 64 + (wid & 1) * 32;
    f32x4 acc[2][2]; ZACC(acc);
    const float* F0 = Of + (size_t)t * (NB * NBEL) + (row0 + r16) * NBEL + kh * 512 + kq * 8;
    const float* F1 = F0 + 16 * NBEL;
    const u16* B0 = wbpos + (size_t)(col0 + r16) * 2048 + 1024 + kh * 512 + kq * 8;
    const u16* B1 = B0 + 16 * 2048;
#pragma unroll 4
    for (int k = 0; k < 512; k += 32) {
      bf16x8 a0 = cvt8(F0 + k), a1 = cvt8(F1 + k);
      bf16x8 b0 = ld8bf(B0 + k), b1 = ld8bf(B1 + k);
      Q4(acc, a0, a1, b0, b1);
    }
    if (kh == 1) red_write(lred[wid], acc, l);
    __syncthreads();
    if (kh == 0) {
      red_add(lred[wid], acc, l);
#pragma unroll
      for (int i = 0; i < 2; ++i)
#pragma unroll
        for (int j = 0; j < 2; ++j)
#pragma unroll
          for (int q = 0; q < 4; ++q) {
            const int row = row0 + i * 16 + kq * 4 + q;
            const int col = col0 + j * 16 + r16;
            hbO[row * NBEL + col] = acc[i][j][q];
          }
    }
  }
}

// ======================= kB: gi+gh+GRU [0..127] | bpri(t-1) [128..255] =======================
// waves 0-3: gi = x @ Wih^T (3 gates, full K); waves 4-7: gh = bprev @ Whh^T (3 gates).
__global__ __launch_bounds__(512, 2) void kB(
    const u16* __restrict__ xbf, const u16* __restrict__ bprev,
    const u16* __restrict__ wih, const u16* __restrict__ whh,
    const float* __restrict__ bih, const float* __restrict__ bhh,
    float* __restrict__ hf, u16* __restrict__ bcur, float* __restrict__ out,
    const u16* __restrict__ wbpri, const float* __restrict__ bbpri,
    u16* __restrict__ hpri, int t) {
  __shared__ float lred[4][3][1024];  // 48KB
  const int l = threadIdx.x & 63, r16 = l & 15, kq = l >> 4;
  const int wid8 = threadIdx.x >> 6;
  const int wid = wid8 & 3, kh = wid8 >> 2;  // kh: 0=gi role, 1=gh role
  if (blockIdx.x < 128) {
    if (t >= NT) return;
    const int g = blockIdx.x, bm = g >> 4, bn = g & 15;
    const int row0 = bm * 64 + (wid >> 1) * 32;
    const int col0 = bn * 64 + (wid & 1) * 32;
    f32x4 ar[2][2], az[2][2], an[2][2];
    ZACC(ar); ZACC(az); ZACC(an);
    const u16* Asrc = (kh == 0) ? xbf : bprev;
    const u16* W = (kh == 0) ? wih : whh;
    const u16* A0 = Asrc + (row0 + r16) * NBEL + kq * 8;
    const u16* A1 = A0 + 16 * NBEL;
    const u16* Br0 = W + (size_t)(col0 + r16) * NBEL + kq * 8;
    const u16* Br1 = Br0 + 16 * NBEL;
    const u16* Bz0 = W + (size_t)(col0 + 1024 + r16) * NBEL + kq * 8;
    const u16* Bz1 = Bz0 + 16 * NBEL;
    const u16* Bn0 = W + (size_t)(col0 + 2048 + r16) * NBEL + kq * 8;
    const u16* Bn1 = Bn0 + 16 * NBEL;
#pragma unroll 4
    for (int k = 0; k < NBEL; k += 32) {
      bf16x8 a0 = ld8bf(A0 + k), a1 = ld8bf(A1 + k);
      bf16x8 b0 = ld8bf(Br0 + k), b1 = ld8bf(Br1 + k);
      Q4(ar, a0, a1, b0, b1);
      bf16x8 c0 = ld8bf(Bz0 + k), c1 = ld8bf(Bz1 + k);
      Q4(az, a0, a1, c0, c1);
      bf16x8 d0 = ld8bf(Bn0 + k), d1 = ld8bf(Bn1 + k);
      Q4(an, a0, a1, d0, d1);
    }
    if (kh == 1) {
      red_write(lred[wid][0], ar, l);
      red_write(lred[wid][1], az, l);
      red_write(lred[wid][2], an, l);
    }
    __syncthreads();
    if (kh == 0) {
      const int base = l * 16;
#pragma unroll
      for (int i = 0; i < 2; ++i)
#pragma unroll
        for (int j = 0; j < 2; ++j)
#pragma unroll
          for (int q = 0; q < 4; ++q) {
            const int row = row0 + i * 16 + kq * 4 + q;
            const int c = col0 + j * 16 + r16;
            const int li = base + (i * 2 + j) * 4 + q;
            const float r = sigm(ar[i][j][q] + bih[c] + lred[wid][0][li] + bhh[c]);
            const float z = sigm(az[i][j][q] + bih[c + 1024] + lred[wid][1][li] + bhh[c + 1024]);
            const float n = tanhf(an[i][j][q] + bih[c + 2048] +
                                  r * (lred[wid][2][li] + bhh[c + 2048]));
            const float h = hf[row * NBEL + c];
            const float bnew = (1.f - z) * n + z * h;
            hf[row * NBEL + c] = bnew;
            bcur[row * NBEL + c] = f2bf(bnew);
            out[OUT_B + (size_t)t * (NB * NBEL) + row * NBEL + c] = bnew;
          }
    }
  } else {
    if (t < 1) return;
    const int g = blockIdx.x - 128, bm = g >> 4, bn = g & 15;
    const int row0 = bm * 64 + (wid >> 1) * 32;
    const int col0 = bn * 64 + (wid & 1) * 32;
    f32x4 acc[2][2]; ZACC(acc);
    const u16* A0 = bprev + (row0 + r16) * NBEL + kh * 512 + kq * 8;
    const u16* A1 = A0 + 16 * NBEL;
    const u16* B0 = wbpri + (size_t)(col0 + r16) * NBEL + kh * 512 + kq * 8;
    const u16* B1 = B0 + 16 * NBEL;
#pragma unroll 4
    for (int k = 0; k < 512; k += 32) {
      bf16x8 a0 = ld8bf(A0 + k), a1 = ld8bf(A1 + k);
      bf16x8 b0 = ld8bf(B0 + k), b1 = ld8bf(B1 + k);
      Q4(acc, a0, a1, b0, b1);
    }
    if (kh == 1) red_write(lred[wid][0], acc, l);
    __syncthreads();
    if (kh == 0) {
      red_add(lred[wid][0], acc, l);
#pragma unroll
      for (int i = 0; i < 2; ++i)
#pragma unroll
        for (int j = 0; j < 2; ++j)
#pragma unroll
          for (int q = 0; q < 4; ++q) {
            const int row = row0 + i * 16 + kq * 4 + q;
            const int col = col0 + j * 16 + r16;
            hpri[row * NBEL + col] = f2bf(fmaxf(acc[i][j][q] + bbpri[col], 0.f));
          }
    }
  }
}

// ======================= kC: hbB(t) [0..127] | spri(t-1) [128..159] =======================
__global__ __launch_bounds__(512, 2) void kC(
    const u16* __restrict__ bcur, const u16* __restrict__ wbpos,
    const float* __restrict__ bbpos, const float* __restrict__ hbO,
    u16* __restrict__ hbbf,
    const u16* __restrict__ hpri, const u16* __restrict__ wspri,
    const float* __restrict__ bspri, const float* __restrict__ npri,
    float* __restrict__ out, int t) {
  __shared__ float lred[4][2][1024];  // 32KB
  const int l = threadIdx.x & 63, r16 = l & 15, kq = l >> 4;
  const int wid8 = threadIdx.x >> 6;
  const int wid = wid8 & 3, kh = wid8 >> 2;
  if (blockIdx.x < 128) {
    if (t >= NT) return;
    const int g = blockIdx.x, bm = g >> 4, bn = g & 15;
    const int row0 = bm * 64 + (wid >> 1) * 32;
    const int col0 = bn * 64 + (wid & 1) * 32;
    f32x4 acc[2][2]; ZACC(acc);
    const u16* A0 = bcur + (row0 + r16) * NBEL + kh * 512 + kq * 8;
    const u16* A1 = A0 + 16 * NBEL;
    const u16* B0 = wbpos + (size_t)(col0 + r16) * 2048 + kh * 512 + kq * 8;
    const u16* B1 = B0 + 16 * 2048;
#pragma unroll 4
    for (int k = 0; k < 512; k += 32) {
      bf16x8 a0 = ld8bf(A0 + k), a1 = ld8bf(A1 + k);
      bf16x8 b0 = ld8bf(B0 + k), b1 = ld8bf(B1 + k);
      Q4(acc, a0, a1, b0, b1);
    }
    if (kh == 1) red_write(lred[wid][0], acc, l);
    __syncthreads();
    if (kh == 0) {
      red_add(lred[wid][0], acc, l);
#pragma unroll
      for (int i = 0; i < 2; ++i)
#pragma unroll
        for (int j = 0; j < 2; ++j)
#pragma unroll
          for (int q = 0; q < 4; ++q) {
            const int row = row0 + i * 16 + kq * 4 + q;
            const int col = col0 + j * 16 + r16;
            const float v = acc[i][j][q] + hbO[row * NBEL + col] + bbpos[col];
            hbbf[row * NBEL + col] = f2bf(fmaxf(v, 0.f));
          }
    }
  } else {
    if (t < 1) return;
    const int g = blockIdx.x - 128, bm = g >> 2, bn = g & 3;
    const int row0 = bm * 64 + (wid >> 1) * 32;
    const int c0 = bn * 64 + (wid & 1) * 32;
    f32x4 am[2][2], ah[2][2];
    ZACC(am); ZACC(ah);
    const u16* A0 = hpri + (row0 + r16) * NBEL + kh * 512 + kq * 8;
    const u16* A1 = A0 + 16 * NBEL;
    const u16* Bm0 = wspri + (size_t)(c0 + r16) * NBEL + kh * 512 + kq * 8;
    const u16* Bm1 = Bm0 + 16 * NBEL;
    const u16* Bh0 = wspri + (size_t)(c0 + 256 + r16) * NBEL + kh * 512 + kq * 8;
    const u16* Bh1 = Bh0 + 16 * NBEL;
#pragma unroll 4
    for (int k = 0; k < 512; k += 32) {
      bf16x8 a0 = ld8bf(A0 + k), a1 = ld8bf(A1 + k);
      bf16x8 m0 = ld8bf(Bm0 + k), m1 = ld8bf(Bm1 + k);
      Q4(am, a0, a1, m0, m1);
      bf16x8 h0 = ld8bf(Bh0 + k), h1 = ld8bf(Bh1 + k);
      Q4(ah, a0, a1, h0, h1);
    }
    if (kh == 1) {
      red_write(lred[wid][0], am, l);
      red_write(lred[wid][1], ah, l);
    }
    __syncthreads();
    if (kh == 0) {
      red_add(lred[wid][0], am, l);
      red_add(lred[wid][1], ah, l);
      const int tt = t - 1;
#pragma unroll
      for (int i = 0; i < 2; ++i)
#pragma unroll
        for (int j = 0; j < 2; ++j)
#pragma unroll
          for (int q = 0; q < 4; ++q) {
            const int row = row0 + i * 16 + kq * 4 + q;
            const int c = c0 + j * 16 + r16;
            const size_t idx = (size_t)tt * (NB * NS) + row * NS + c;
            const float mu = am[i][j][q] + bspri[c];
            const float hp = ah[i][j][q] + bspri[c + 256];
            const float sd = softplus_(hp) + 0.1f;
            out[OUT_SPRI + idx] = mu + sd * npri[idx];
            out[OUT_MUPRI + idx] = mu;
            out[OUT_STDPRI + idx] = sd;
          }
    }
  }
}

// ======================= kD: spos(t) [32 blocks] =======================
__global__ __launch_bounds__(512, 2) void kD(
    const u16* __restrict__ hbbf, const u16* __restrict__ wspos,
    const float* __restrict__ bspos, const float* __restrict__ npos,
    const float* __restrict__ Mptr, float* __restrict__ out,
    u16* __restrict__ smask, int t) {
  __shared__ float lred[4][2][1024];
  const int l = threadIdx.x & 63, r16 = l & 15, kq = l >> 4;
  const int wid8 = threadIdx.x >> 6;
  const int wid = wid8 & 3, kh = wid8 >> 2;
  const int g = blockIdx.x, bm = g >> 2, bn = g & 3;
  const int row0 = bm * 64 + (wid >> 1) * 32;
  const int c0 = bn * 64 + (wid & 1) * 32;
  f32x4 am[2][2], ah[2][2];
  ZACC(am); ZACC(ah);
  const u16* A0 = hbbf + (row0 + r16) * NBEL + kh * 512 + kq * 8;
  const u16* A1 = A0 + 16 * NBEL;
  const u16* Bm0 = wspos + (size_t)(c0 + r16) * NBEL + kh * 512 + kq * 8;
  const u16* Bm1 = Bm0 + 16 * NBEL;
  const u16* Bh0 = wspos + (size_t)(c0 + 256 + r16) * NBEL + kh * 512 + kq * 8;
  const u16* Bh1 = Bh0 + 16 * NBEL;
#pragma unroll 4
  for (int k = 0; k < 512; k += 32) {
    bf16x8 a0 = ld8bf(A0 + k), a1 = ld8bf(A1 + k);
    bf16x8 m0 = ld8bf(Bm0 + k), m1 = ld8bf(Bm1 + k);
    Q4(am, a0, a1, m0, m1);
    bf16x8 h0 = ld8bf(Bh0 + k), h1 = ld8bf(Bh1 + k);
    Q4(ah, a0, a1, h0, h1);
  }
  if (kh == 1) {
    red_write(lred[wid][0], am, l);
    red_write(lred[wid][1], ah, l);
  }
  __syncthreads();
  if (kh == 0) {
    red_add(lred[wid][0], am, l);
    red_add(lred[wid][1], ah, l);
#pragma unroll
    for (int i = 0; i < 2; ++i)
#pragma unroll
      for (int j = 0; j < 2; ++j)
#pragma unroll
        for (int q = 0; q < 4; ++q) {
          const int row = row0 + i * 16 + kq * 4 + q;
          const int c = c0 + j * 16 + r16;
          const float mu = am[i][j][q] + bspos[c];
          const float hq = ah[i][j][q] + bspos[c + 256];
          const float sd = softplus_(hq) + 0.1f;
          const size_t idx = (size_t)t * (NB * NS) + row * NS + c;
          const float sq = mu + sd * npos[idx];
          out[OUT_SPOS + idx] = sq;
          out[OUT_MUPOS + idx] = mu;
          out[OUT_STDPOS + idx] = sd;
          const float mn = (t < NT - 1) ? Mptr[(t + 1) * NB + row] : 1.f;
          smask[row * NS + c] = f2bf(sq * mn);
        }
  }
}

extern "C" void kernel_launch(void* const* d_in, const int* in_sizes, int n_in,
                              void* d_out, int out_size, void* d_ws, size_t ws_size,
                              hipStream_t stream) {
  const float* s0 = (const float*)d_in[0];
  const float* Af = (const float*)d_in[1];
  const float* b0 = (const float*)d_in[2];
  const float* Of = (const float*)d_in[3];
  const float* Mp = (const float*)d_in[4];
  const float* npri = (const float*)d_in[5];
  const float* npos = (const float*)d_in[6];
  const float* Wsa = (const float*)d_in[7];
  const float* bsa = (const float*)d_in[8];
  const float* Wih = (const float*)d_in[9];
  const float* bih = (const float*)d_in[10];
  const float* Whh = (const float*)d_in[11];
  const float* bhh = (const float*)d_in[12];
  const float* Wbpri = (const float*)d_in[13];
  const float* bbpri = (const float*)d_in[14];
  const float* Wspri = (const float*)d_in[15];
  const float* bspri = (const float*)d_in[16];
  const float* Wbpos = (const float*)d_in[17];
  const float* bbpos = (const float*)d_in[18];
  const float* Wspos = (const float*)d_in[19];
  const float* bspos = (const float*)d_in[20];

  float* out = (float*)d_out;
  char* ws = (char*)d_ws;
  u16* wbase   = (u16*)ws;
  u16* wsa_b   = wbase;
  u16* wih_b   = wbase + 327680;
  u16* whh_b   = wbase + 3473408;
  u16* wbpri_b = wbase + 6619136;
  u16* wspri_b = wbase + 7667712;
  u16* wbpos_b = wbase + 8192000;
  u16* wspos_b = wbase + 10289152;
  // weights end at byte 21,626,880
  u16*   smask = (u16*)  (ws + 21626880);  // [512,256]  bf16  256KB
  u16*   bbf0  = (u16*)  (ws + 21889024);  // [512,1024] bf16  1MB
  u16*   bbf1  = (u16*)  (ws + 22937600);  // [512,1024] bf16  1MB
  float* hf    = (float*)(ws + 23986176);  // [512,1024] f32   2MB
  u16*   xbf   = (u16*)  (ws + 26083328);  // [512,1024] bf16  1MB
  float* hbO   = (float*)(ws + 27131904);  // [512,1024] f32   2MB
  u16*   hbbf  = (u16*)  (ws + 29229056);  // [512,1024] bf16  1MB
  u16*   hpri  = (u16*)  (ws + 30277632);  // [512,1024] bf16  1MB
  // ws end: 31,326,208 bytes

  cvt_weights_k<<<2048, 256, 0, stream>>>(Wsa, Wih, Whh, Wbpri, Wspri, Wbpos,
                                          Wspos, wbase);
  init_carry_k<<<2048, 256, 0, stream>>>(s0, b0, Mp, smask, bbf0, hf);

  for (int t = 0; t < NT; ++t) {
    const u16* bprev = (t & 1) ? bbf1 : bbf0;
    u16* bcur = (t & 1) ? bbf0 : bbf1;
    kA<<<256, 512, 0, stream>>>(smask, Af, wsa_b, bsa, xbf, Of, wbpos_b, hbO, t);
    kB<<<256, 512, 0, stream>>>(xbf, bprev, wih_b, whh_b, bih, bhh, hf, bcur,
                                out, wbpri_b, bbpri, hpri, t);
    kC<<<160, 512, 0, stream>>>(bcur, wbpos_b, bbpos, hbO, hbbf,
                                hpri, wspri_b, bspri, npri, out, t);
    kD<<<32, 512, 0, stream>>>(hbbf, wspos_b, bspos, npos, Mp, out, smask, t);
  }
  // tail: bpri(63) then spri(63)
  {
    const int t = NT;  // even -> bprev = bbf0 = bnew(63)
    const u16* bprev = (t & 1) ? bbf1 : bbf0;
    u16* bcur = (t & 1) ? bbf0 : bbf1;
    kB<<<256, 512, 0, stream>>>(xbf, bprev, wih_b, whh_b, bih, bhh, hf, bcur,
                                out, wbpri_b, bbpri, hpri, t);
    kC<<<160, 512, 0, stream>>>(bcur, wbpos_b, bbpos, hbO, hbbf,
                                hpri, wspri_b, bspri, npri, out, t);
  }
}